// Round 5
// baseline (549.023 us; speedup 1.0000x reference)
//
#include <hip/hip_runtime.h>

// Event-warp + bilinear splat, v16 = STRUCTURAL PIVOT: single-pass direct
// global-atomic splat.
//   Post-mortem v13/v14/v15: three K1 micro-restructures (occupancy, load
//   ILP, scratch elimination) ALL null at ~46-50us; duration invariant
//   under occupancy 35<->55%, VALUBusy 10-15%, HBM 17%. Conclusion: the
//   two-pass sort/splat machinery itself (2M ranked 8-B records with
//   partial-line RMW amplification, 600-tile LDS hist+scan per block,
//   then a ~40us K2 re-read) costs more than the scatter problem it
//   solves. Uniform-random events => ~2 atomics per output cell, so
//   direct device-scope f32 atomicAdd contention is negligible.
//   v16: one kernel, one thread per event, 8 atomicAdd(float) per event
//   (4 bilinear corners x {count, ts} planes). Cost model: 9.6M atomic
//   lane-transactions / 256 CU ~ 16us addr-divergence floor + ~10us
//   streams; predicted total ~35-55us vs 128us for two-pass.
//   XCD-affinity swizzle kept: batch b -> XCD pair {2b,2b+1}; per-batch
//   flow (2.45 MB) and output (4.9 MB) then live in a 2-XCD L2 slice.
// Inputs (setup_inputs order):
//   d_in[0] flow  : float32 [B,2,H,W]   (ch0 = x-flow, ch1 = y-flow)
//   d_in[1] ts    : float32 [B,N,1]
//   d_in[2] ev_y  : int32   [B,N]
//   d_in[3] ev_x  : int32   [B,N]
//   d_in[4] pol   : int32   [B,N]  (1 = positive, 0 = negative)
// Output: float32 [B,4,H,W] = (iwe_pos, iwe_neg, iwe_pos_ts, iwe_neg_ts)

#define IMG_H 480
#define IMG_W 640
#define NB 4

#define K_THREADS 256

// ---------------------------------------------------------------------------
__device__ __forceinline__ void
splat_event(const float* __restrict__ flow, const float* __restrict__ ts,
            const int* __restrict__ ev_y, const int* __restrict__ ev_x,
            const int* __restrict__ pol, float* __restrict__ out,
            int b, int idx, int N) {
    const int i = b * N + idx;

    // coalesced event-field loads (4 independent streams)
    const int   y = ev_y[i];
    const int   x = ev_x[i];
    const float t = ts[i];
    const int   p = pol[i];

    // random flow gathers (2 per event)
    const float* fb = flow + (size_t)b * 2 * IMG_H * IMG_W;
    const int pix = y * IMG_W + x;
    const float fx = fb[pix];
    const float fy = fb[IMG_H * IMG_W + pix];

    const float dt = 1.0f - t;
    const float wy = (float)y + dt * fy;
    const float wx = (float)x + dt * fx;
    const float nts = 1.0f - fabsf(1.0f - t);

    const float byf = floorf(wy), bxf = floorf(wx);
    const int iy0 = (int)byf, ix0 = (int)bxf;
    const float ay = wy - byf, ax = wx - bxf;
    const float wyv[2] = {1.0f - ay, ay};
    const float wxv[2] = {1.0f - ax, ax};

    float* out_c = out + ((size_t)b * 4 + (p ? 0 : 1)) * IMG_H * IMG_W;
    float* out_t = out_c + 2 * IMG_H * IMG_W;

    #pragma unroll
    for (int dy = 0; dy < 2; ++dy) {
        const int gy = iy0 + dy;
        if ((unsigned)gy >= (unsigned)IMG_H) continue;
        #pragma unroll
        for (int dx = 0; dx < 2; ++dx) {
            const int gx = ix0 + dx;
            if ((unsigned)gx >= (unsigned)IMG_W) continue;
            const float w = wyv[dy] * wxv[dx];
            const int o = gy * IMG_W + gx;
            atomicAdd(out_c + o, w);
            atomicAdd(out_t + o, w * nts);
        }
    }
}

// ---------------------------------------------------------------------------
// B==4 path: XCD-affinity swizzle. block L -> XCD L%8 (heuristic);
// batch = bits[2:1] of L -> XCDs {2b,2b+1}; chunk = (L>>3)*2 + (L&1).
__global__ void __launch_bounds__(K_THREADS)
event_splat_direct(const float* __restrict__ flow, const float* __restrict__ ts,
                   const int* __restrict__ ev_y, const int* __restrict__ ev_x,
                   const int* __restrict__ pol, float* __restrict__ out,
                   int N, int nchunk) {
    const int L = blockIdx.x;
    const int b = (L >> 1) & 3;
    const int chunk = (L >> 3) * 2 + (L & 1);
    if (chunk >= nchunk) return;
    const int idx = chunk * K_THREADS + threadIdx.x;
    if (idx >= N) return;
    splat_event(flow, ts, ev_y, ev_x, pol, out, b, idx, N);
}

// ---------------------------------------------------------------------------
// Generic-B fallback: plain linear grid.
__global__ void __launch_bounds__(K_THREADS)
event_splat_fallback(const float* __restrict__ flow, const float* __restrict__ ts,
                     const int* __restrict__ ev_y, const int* __restrict__ ev_x,
                     const int* __restrict__ pol, float* __restrict__ out,
                     int N, int total) {
    const int i = blockIdx.x * blockDim.x + threadIdx.x;
    if (i >= total) return;
    splat_event(flow, ts, ev_y, ev_x, pol, out, i / N, i % N, N);
}

// ---------------------------------------------------------------------------
extern "C" void kernel_launch(void* const* d_in, const int* in_sizes, int n_in,
                              void* d_out, int out_size, void* d_ws, size_t ws_size,
                              hipStream_t stream) {
    const float* flow = (const float*)d_in[0];
    const float* ts   = (const float*)d_in[1];
    const int*   ev_y = (const int*)d_in[2];
    const int*   ev_x = (const int*)d_in[3];
    const int*   pol  = (const int*)d_in[4];
    float* out = (float*)d_out;

    const int total = in_sizes[2];                  // B*N
    const int B = out_size / (4 * IMG_H * IMG_W);
    const int N = total / B;

    hipMemsetAsync(d_out, 0, (size_t)out_size * sizeof(float), stream);

    if (B == NB) {
        const int nchunk = (N + K_THREADS - 1) / K_THREADS;   // 1172
        const int g = 8 * ((nchunk + 1) / 2);                 // 4688
        event_splat_direct<<<g, K_THREADS, 0, stream>>>(
            flow, ts, ev_y, ev_x, pol, out, N, nchunk);
        return;
    }

    const int blocks = (total + K_THREADS - 1) / K_THREADS;
    event_splat_fallback<<<blocks, K_THREADS, 0, stream>>>(flow, ts, ev_y, ev_x,
                                                           pol, out, N, total);
}

// Round 6
// 122.359 us; speedup vs baseline: 4.4870x; 4.4870x over previous
//
#include <hip/hip_runtime.h>

// Event-warp + bilinear splat, v17 = v15 + 32x32 ownership tiles.
//   Post-mortem v16 (direct-atomic pivot, 549us): device-scope atomicAdd
//   RMWs at the memory-side coherence point (~20G atomic/s, 31 B HBM write
//   per atomic, WRITE_SIZE 298 MB) -> two-pass structure validated.
//   That measurement re-prices v15's K1: Phase B's ~576K device-scope
//   cursor atomics (1176 blocks x ~490 nonzero tiles) are ~20+us of K1's
//   46us -- the occupancy/ILP/scratch-invariant floor seen in v13-v15.
//   v17: ownership tile 16x32 -> 32x32. Phase-B atomics 576K->~341K
//   (300 tiles/batch), dup factor 1.096->1.063, cursor lines 2400->1200,
//   K2 blocks 1200 @ 16 KB LDS. Quantization rescaled (scale 1024 both
//   axes, span 34 units).
//   K1 warp_scatter: warp events + direct dest-tile counting scatter
//       (LDS hist+rank, padded cursors, 8-B records). XCD-affinity swizzle:
//       batch b runs on XCDs {2b,2b+1} -> per-XCD L2 holds ONE batch's flow.
//   K2 splat: one block per ownership tile, same swizzle (drec L2 affinity);
//       paired uint4 loads; (w, w*nts) Q20-packed ds_add_u64; fused spill;
//       pure float4 writeout (no out-memset needed).
// Inputs (setup_inputs order):
//   d_in[0] flow  : float32 [B,2,H,W]   (ch0 = x-flow, ch1 = y-flow)
//   d_in[1] ts    : float32 [B,N,1]
//   d_in[2] ev_y  : int32   [B,N]
//   d_in[3] ev_x  : int32   [B,N]
//   d_in[4] pol   : int32   [B,N]  (1 = positive, 0 = negative)
// Output: float32 [B,4,H,W] = (iwe_pos, iwe_neg, iwe_pos_ts, iwe_neg_ts)

#define IMG_H 480
#define IMG_W 640

#define OT_H 32
#define OT_W 32
#define OTY (IMG_H / OT_H)        // 15
#define OTX (IMG_W / OT_W)        // 20
#define OT_PER_B (OTY * OTX)      // 300
#define NB 4
#define NT (NB * OT_PER_B)        // 1200

#define ACC_PLANE (OT_H * OT_W)   // 1024 cells

// ws layout (byte offsets)
#define CURS_STRIDE 16                  // u32 stride -> 64 B padded lines
#define WS_CURS 0                       // NT * 64 B = 76800
#define WS_SPILLCNT 76800               // 4 B
#define WS_SPILL 81920                  // SPILL_CAP * 16 B = 512 KB
#define SPILL_CAP 32768
#define WS_RECS 606208                  // drecs: NT * cap * 8 B

#define K1_THREADS 256
#define K1_IPT 4
#define K1_CHUNK (K1_THREADS * K1_IPT)  // 1024 events per block

#define DUP_INVALID 0xFFFFFFFFu

// tile-local coord quantization: q = (w - 32*dt + 1) * 1024, span [0, 34816)
#define QSCALE 1024.0f
#define INV_QSCALE 9.765625e-04f

#define Q20 1048576.0f
#define INV_Q20 9.5367431640625e-07f

// ---------------------------------------------------------------------------
// K1: warp + direct dest-tile counting scatter. XCD-affinity swizzle:
// block L -> XCD L%8 (heuristic); batch = bits[2:1] of L -> XCDs {2b,2b+1}.
__global__ void __launch_bounds__(K1_THREADS)
warp_scatter_kernel(const float* __restrict__ flow, const float* __restrict__ ts,
                    const int* __restrict__ ev_y, const int* __restrict__ ev_x,
                    const int* __restrict__ pol,
                    unsigned* __restrict__ dcurs, unsigned* __restrict__ spillcnt,
                    float4* __restrict__ spill, uint2* __restrict__ drecs,
                    int N, int cap, int nchunk) {
    __shared__ unsigned lh[OT_PER_B];     // per-dest-tile block-local counts
    __shared__ unsigned lbase[OT_PER_B];  // reserved global bases
    const int tid = threadIdx.x;
    const int L = blockIdx.x;
    const int b = (L >> 1) & 3;                    // batch -> XCD pair
    const int chunk = (L >> 3) * 2 + (L & 1);
    if (chunk >= nchunk) return;
    const int base = chunk * K1_CHUNK;

    for (int j = tid; j < OT_PER_B; j += K1_THREADS) lh[j] = 0;

    // Phase A1: coalesced event-field loads — all 4*IPT independent.
    int   eyK[K1_IPT], exK[K1_IPT], poK[K1_IPT];
    float tsK[K1_IPT];
    bool  vK[K1_IPT];
    #pragma unroll
    for (int k = 0; k < K1_IPT; ++k) {
        const int idx = base + k * K1_THREADS + tid;
        vK[k] = (idx < N);
        const int i = b * N + (vK[k] ? idx : 0);
        eyK[k] = ev_y[i];
        exK[k] = ev_x[i];
        tsK[k] = ts[i];
        poK[k] = pol[i];
    }

    // Phase A2: random flow gathers — 2*IPT loads issued back-to-back.
    const float* fb = flow + (size_t)b * 2 * IMG_H * IMG_W;
    float fxK[K1_IPT], fyK[K1_IPT];
    #pragma unroll
    for (int k = 0; k < K1_IPT; ++k) {
        const int pix = eyK[k] * IMG_W + exK[k];
        fxK[k] = fb[pix];
        fyK[k] = fb[IMG_H * IMG_W + pix];
    }

    __syncthreads();   // lh zeroing visible before ranking

    // Phase A3: warp + LDS rank. STATIC 4-slot dup table (rule #20):
    // slots = (row0/row1) x (col0/col1) tile combos; DUP_INVALID = unused.
    float wyK[K1_IPT], wxK[K1_IPT];
    unsigned metaK[K1_IPT];               // qt | pol<<15 (drec.y)
    unsigned dupS[K1_IPT][4];             // lt<<16 | rank, or DUP_INVALID

    #pragma unroll
    for (int k = 0; k < K1_IPT; ++k) {
        float wy = 0.f, wx = 0.f;
        unsigned meta = 0;
        unsigned d0 = DUP_INVALID, d1 = DUP_INVALID,
                 d2 = DUP_INVALID, d3 = DUP_INVALID;
        if (vK[k]) {
            const float t = tsK[k];
            const float dt = 1.0f - t;
            wy = (float)eyK[k] + dt * fyK[k];
            wx = (float)exK[k] + dt * fxK[k];
            const float nts = 1.0f - fabsf(1.0f - t);
            const int p = poK[k] & 1;
            int qt = __float2int_rn(nts * 32767.0f);
            qt = min(max(qt, 0), 32767);
            meta = (unsigned)qt | ((unsigned)p << 15);

            const int iy0 = (int)floorf(wy);
            const int ix0 = (int)floorf(wx);
            const int ry0 = iy0 >> 5;
            const int ry1 = (iy0 + 1) >> 5;
            const bool cy0 = (iy0 >= 0) && (iy0 < IMG_H);
            const bool cy1 = (iy0 + 1 >= 0) && (iy0 + 1 < IMG_H)
                             && (!cy0 || ry1 != ry0);
            const int rx0 = ix0 >> 5;
            const int rx1 = (ix0 + 1) >> 5;
            const bool cx0 = (ix0 >= 0) && (ix0 < IMG_W);
            const bool cx1 = (ix0 + 1 >= 0) && (ix0 + 1 < IMG_W)
                             && (!cx0 || rx1 != rx0);

            if (cy0 && cx0) {
                const unsigned lt = (unsigned)(ry0 * OTX + rx0);
                d0 = (lt << 16) | atomicAdd(&lh[lt], 1u);
            }
            if (cy0 && cx1) {
                const unsigned lt = (unsigned)(ry0 * OTX + rx1);
                d1 = (lt << 16) | atomicAdd(&lh[lt], 1u);
            }
            if (cy1 && cx0) {
                const unsigned lt = (unsigned)(ry1 * OTX + rx0);
                d2 = (lt << 16) | atomicAdd(&lh[lt], 1u);
            }
            if (cy1 && cx1) {
                const unsigned lt = (unsigned)(ry1 * OTX + rx1);
                d3 = (lt << 16) | atomicAdd(&lh[lt], 1u);
            }
        }
        wyK[k] = wy; wxK[k] = wx; metaK[k] = meta;
        dupS[k][0] = d0; dupS[k][1] = d1; dupS[k][2] = d2; dupS[k][3] = d3;
    }
    __syncthreads();

    // Phase B: reserve per-tile global ranges (1 padded atomic per nonzero).
    // These are device-scope (memory-side RMW, ~expensive: v16 measurement)
    // -> count minimized by the 32x32 tiling.
    for (int j = tid; j < OT_PER_B; j += K1_THREADS) {
        const unsigned n = lh[j];
        lbase[j] = n ? atomicAdd(&dcurs[(size_t)(b * OT_PER_B + j) * CURS_STRIDE], n)
                     : 0u;
    }
    __syncthreads();

    // Phase C: write dest-quantized records (static slot iteration)
    #pragma unroll
    for (int k = 0; k < K1_IPT; ++k) {
        #pragma unroll
        for (int d = 0; d < 4; ++d) {
            const unsigned dp = dupS[k][d];
            if (dp == DUP_INVALID) continue;
            const unsigned lt = dp >> 16;
            const unsigned rk = dp & 0xFFFFu;
            const int dty = (int)(lt / OTX);
            const int dtx = (int)(lt % OTX);
            const unsigned slot = lbase[lt] + rk;
            if (slot < (unsigned)cap) {
                int qy = __float2int_rn((wyK[k] - 32.0f * dty + 1.0f) * QSCALE);
                int qx = __float2int_rn((wxK[k] - 32.0f * dtx + 1.0f) * QSCALE);
                qy = min(max(qy, 0), 65535);
                qx = min(max(qx, 0), 65535);
                uint2 dr;
                dr.x = (unsigned)qy | ((unsigned)qx << 16);
                dr.y = metaK[k];
                drecs[(size_t)(b * OT_PER_B + lt) * cap + slot] = dr;
            } else {
                // restricted spill: applied only by tile (dty,dtx)
                const unsigned g = atomicAdd(spillcnt, 1u);
                if (g < SPILL_CAP) {
                    float4 s;
                    s.x = wyK[k]; s.y = wxK[k];
                    s.z = (float)(metaK[k] & 0x7FFFu) * (1.0f / 32767.0f);
                    s.w = __uint_as_float(0x80000000u
                            | (unsigned)((b << 1) | (metaK[k] >> 15))
                            | ((unsigned)dty << 8) | ((unsigned)dtx << 16));
                    spill[g] = s;
                }
            }
        }
    }
}

// ---------------------------------------------------------------------------
// K2: one block per ownership tile, same XCD-affinity swizzle.
__device__ __forceinline__ void
splat_rec(unsigned rx_, unsigned ry_, unsigned long long* __restrict__ acc64) {
    const float ry  = (float)(rx_ & 0xFFFFu) * INV_QSCALE - 1.0f;
    const float rx  = (float)(rx_ >> 16)     * INV_QSCALE - 1.0f;
    const float nts = (float)(ry_ & 0x7FFFu) * (1.0f / 32767.0f);
    const int p = (int)((ry_ >> 15) & 1u);
    const float byf = floorf(ry), bxf = floorf(rx);
    const int iy0 = (int)byf, ix0 = (int)bxf;
    const float ay = ry - byf, ax = rx - bxf;
    const float wyv[2] = {1.0f - ay, ay};
    const float wxv[2] = {1.0f - ax, ax};
    unsigned long long* accp = acc64 + (p ? 0 : 1) * ACC_PLANE;
    #pragma unroll
    for (int dy = 0; dy < 2; ++dy) {
        const int gy = iy0 + dy;
        if ((unsigned)gy >= (unsigned)OT_H) continue;
        #pragma unroll
        for (int dx = 0; dx < 2; ++dx) {
            const int gx = ix0 + dx;
            if ((unsigned)gx >= (unsigned)OT_W) continue;
            const float w = wyv[dy] * wxv[dx];
            const unsigned qw  = __float2uint_rn(w * Q20);
            const unsigned qwt = __float2uint_rn(w * nts * Q20);
            atomicAdd(&accp[gy * OT_W + gx],
                      ((unsigned long long)qwt << 32) | (unsigned long long)qw);
        }
    }
}

__global__ void __launch_bounds__(256)
splat_kernel(const uint2* __restrict__ drecs, const unsigned* __restrict__ dcurs,
             const float4* __restrict__ spill, const unsigned* __restrict__ spillcnt,
             float* __restrict__ out, int cap) {
    __shared__ unsigned long long acc64[2 * ACC_PLANE];  // [pol(pos,neg)][cell]
    const int L = blockIdx.x;
    const int myb = (L >> 1) & 3;                  // batch -> XCD pair
    const int rb  = (L >> 3) * 2 + (L & 1);        // 0..299
    const int tile = myb * OT_PER_B + rb;
    const int tid = threadIdx.x;
    #pragma unroll
    for (int j = tid; j < 2 * ACC_PLANE; j += 256) acc64[j] = 0ull;
    __syncthreads();

    const int sy  = rb / OTX;
    const int sx  = rb % OTX;

    const unsigned cnt = min(dcurs[(size_t)tile * CURS_STRIDE], (unsigned)cap);
    const uint2* recs = drecs + (size_t)tile * cap;
    const uint4* base4 = (const uint4*)recs;
    const unsigned npair = cnt >> 1;
    for (unsigned u = tid; u < npair; u += 256) {
        const uint4 q = base4[u];          // two records
        splat_rec(q.x, q.y, acc64);
        splat_rec(q.z, q.w, acc64);
    }
    if ((cnt & 1u) && tid == 0) {
        const uint2 r = recs[cnt - 1];
        splat_rec(r.x, r.y, acc64);
    }

    // fused spill application (normally zero records)
    const unsigned nsp = min(*spillcnt, (unsigned)SPILL_CAP);
    for (unsigned i = tid; i < nsp; i += 256) {
        const float4 s = spill[i];
        const unsigned meta = __float_as_uint(s.w);
        if ((int)((meta >> 1) & 3u) != myb) continue;
        if (meta & 0x80000000u) {   // restricted to one dest tile
            if ((int)((meta >> 8) & 31u) != sy || (int)((meta >> 16) & 31u) != sx)
                continue;
        }
        const int p = (int)(meta & 1u);
        const float wy = s.x, wx = s.y, nts = s.z;
        const float byf = floorf(wy), bxf = floorf(wx);
        const int iy0 = (int)byf, ix0 = (int)bxf;
        const float ay = wy - byf, ax = wx - bxf;
        const float wyv[2] = {1.0f - ay, ay};
        const float wxv[2] = {1.0f - ax, ax};
        unsigned long long* accp = acc64 + (p ? 0 : 1) * ACC_PLANE;
        #pragma unroll
        for (int dy = 0; dy < 2; ++dy) {
            const int gy = iy0 + dy;
            if ((gy >> 5) != sy) continue;       // ownership (global coords)
            #pragma unroll
            for (int dx = 0; dx < 2; ++dx) {
                const int gx = ix0 + dx;
                if ((gx >> 5) != sx) continue;
                const float w = wyv[dy] * wxv[dx];
                const unsigned qw  = __float2uint_rn(w * Q20);
                const unsigned qwt = __float2uint_rn(w * nts * Q20);
                atomicAdd(&accp[(gy & 31) * OT_W + (gx & 31)],
                          ((unsigned long long)qwt << 32) | (unsigned long long)qw);
            }
        }
    }
    __syncthreads();

    const int y0 = sy * OT_H;
    const int x0 = sx * OT_W;
    float* outb = out + (size_t)myb * 4 * IMG_H * IMG_W;
    for (int q = tid; q < 2 * (ACC_PLANE / 4); q += 256) {
        const int pl  = q / (ACC_PLANE / 4);     // 0 = pos, 1 = neg
        const int rem = q % (ACC_PLANE / 4);
        const int ry  = rem / (OT_W / 4);
        const int rx4 = rem % (OT_W / 4);
        float4 c4, t4;
        const unsigned long long* cell = acc64 + pl * ACC_PLANE + rem * 4;
        float* c = &c4.x; float* t = &t4.x;
        #pragma unroll
        for (int j = 0; j < 4; ++j) {
            const unsigned long long v = cell[j];
            c[j] = (float)(unsigned)(v & 0xFFFFFFFFull) * INV_Q20;
            t[j] = (float)(unsigned)(v >> 32) * INV_Q20;
        }
        const size_t off = (size_t)(y0 + ry) * IMG_W + x0 + rx4 * 4;
        *(float4*)(outb + (size_t)pl * IMG_H * IMG_W + off) = c4;
        *(float4*)(outb + (size_t)(pl + 2) * IMG_H * IMG_W + off) = t4;
    }
}

// ---------------------------------------------------------------------------
__device__ __forceinline__ void
warp_from(const float* __restrict__ flow, int b, int y, int x, float t,
          float& wy, float& wx, float& nts) {
    const float* fb = flow + (size_t)b * 2 * IMG_H * IMG_W;
    const int pix = y * IMG_W + x;
    const float fx = fb[pix];
    const float fy = fb[IMG_H * IMG_W + pix];
    const float dt = 1.0f - t;
    wy = (float)y + dt * fy;
    wx = (float)x + dt * fx;
    nts = 1.0f - fabsf(1.0f - t);
}

// Last-resort fallback: direct global atomics (needs zeroed out).
__global__ void __launch_bounds__(256)
event_splat_fallback(const float* __restrict__ flow, const float* __restrict__ ts,
                     const int* __restrict__ ev_y, const int* __restrict__ ev_x,
                     const int* __restrict__ pol, float* __restrict__ out,
                     int N, int total) {
    const int i = blockIdx.x * blockDim.x + threadIdx.x;
    if (i >= total) return;
    const int b = i / N;
    float wy, wx, nts;
    warp_from(flow, b, ev_y[i], ev_x[i], ts[i], wy, wx, nts);
    const int p = pol[i];
    const float byf = floorf(wy), bxf = floorf(wx);
    const int iy0 = (int)byf, ix0 = (int)bxf;
    const float ay = wy - byf, ax = wx - bxf;
    const float wyv[2] = {1.0f - ay, ay};
    const float wxv[2] = {1.0f - ax, ax};
    float* out_c = out + ((size_t)b * 4 + (p ? 0 : 1)) * IMG_H * IMG_W;
    float* out_t = out_c + 2 * IMG_H * IMG_W;
    #pragma unroll
    for (int dy = 0; dy < 2; ++dy) {
        const int gy = iy0 + dy;
        if (gy < 0 || gy >= IMG_H) continue;
        #pragma unroll
        for (int dx = 0; dx < 2; ++dx) {
            const int gx = ix0 + dx;
            if (gx < 0 || gx >= IMG_W) continue;
            const float w = wyv[dy] * wxv[dx];
            const int o = gy * IMG_W + gx;
            atomicAdd(out_c + o, w);
            atomicAdd(out_t + o, w * nts);
        }
    }
}

// ---------------------------------------------------------------------------
extern "C" void kernel_launch(void* const* d_in, const int* in_sizes, int n_in,
                              void* d_out, int out_size, void* d_ws, size_t ws_size,
                              hipStream_t stream) {
    const float* flow = (const float*)d_in[0];
    const float* ts   = (const float*)d_in[1];
    const int*   ev_y = (const int*)d_in[2];
    const int*   ev_x = (const int*)d_in[3];
    const int*   pol  = (const int*)d_in[4];
    float* out = (float*)d_out;

    const int total = in_sizes[2];                  // B*N
    const int B = out_size / (4 * IMG_H * IMG_W);
    const int N = total / B;
    char* ws = (char*)d_ws;

    // cap slots per dest tile: drec 8 B/slot. Mean load ~1063/tile
    // (300K events/batch x 1.063 dup / 300 tiles); gate at mean+~6.5 sigma,
    // spill absorbs stragglers.
    int cap = 0;
    if (ws_size > (size_t)WS_RECS)
        cap = (int)((ws_size - WS_RECS) / ((size_t)NT * 8));
    if (cap > 4096) cap = 4096;
    cap &= ~3;

    if (B == NB && cap >= 1280) {
        unsigned* dcurs    = (unsigned*)(ws + WS_CURS);
        unsigned* spillcnt = (unsigned*)(ws + WS_SPILLCNT);
        float4*   spill    = (float4*)(ws + WS_SPILL);
        uint2*    drecs    = (uint2*)(ws + WS_RECS);

        hipMemsetAsync(ws, 0, WS_SPILL, stream);    // dcurs + spillcnt

        const int nchunk = (N + K1_CHUNK - 1) / K1_CHUNK;            // 293
        const int g1 = 8 * ((nchunk + 1) / 2);                       // 1176
        warp_scatter_kernel<<<g1, K1_THREADS, 0, stream>>>(
            flow, ts, ev_y, ev_x, pol, dcurs, spillcnt, spill, drecs,
            N, cap, nchunk);
        splat_kernel<<<NT, 256, 0, stream>>>(drecs, dcurs, spill, spillcnt,
                                             out, cap);
        return;
    }

    // last resort
    hipMemsetAsync(d_out, 0, (size_t)out_size * sizeof(float), stream);
    const int blocks = (total + 255) / 256;
    event_splat_fallback<<<blocks, 256, 0, stream>>>(flow, ts, ev_y, ev_x, pol,
                                                     out, N, total);
}

// Round 7
// 119.072 us; speedup vs baseline: 4.6109x; 1.0276x over previous
//
#include <hip/hip_runtime.h>

// Event-warp + bilinear splat, v18 = v17 + K1_IPT 8 (2048-event blocks).
//   Ledger so far: v16 priced device-scope atomics (~23-25 ns marginal,
//   memory-side RMW); v17 (32x32 tiles, -235K cursor atomics) = -6us total,
//   K1 dropped below the harness's 44us workspace-poison fill. The fill
//   (256 MiB @ 6.1 TB/s) is fixed timed harness cost.
//   v18: IPT 4->8 -> 588 blocks: Phase-B cursor atomics 341K -> ~174K
//   (-4us at measured price), Phase-C runs 3.4->6.8 recs (54 B) per
//   (tile,block) -> less partial-line RMW (WRITE 42->~36 MB). Occupancy
//   falls to ~2.3 blocks/CU -- proven slack (v13: K1 invariant 35<->55%).
//   K1 warp_scatter: warp events + direct dest-tile counting scatter
//       (LDS hist+rank, padded cursors, 8-B records). XCD-affinity swizzle:
//       batch b runs on XCDs {2b,2b+1} -> per-XCD L2 holds ONE batch's flow.
//   K2 splat: one block per ownership tile, same swizzle (drec L2 affinity);
//       paired uint4 loads; (w, w*nts) Q20-packed ds_add_u64; fused spill;
//       pure float4 writeout (no out-memset needed).
// Inputs (setup_inputs order):
//   d_in[0] flow  : float32 [B,2,H,W]   (ch0 = x-flow, ch1 = y-flow)
//   d_in[1] ts    : float32 [B,N,1]
//   d_in[2] ev_y  : int32   [B,N]
//   d_in[3] ev_x  : int32   [B,N]
//   d_in[4] pol   : int32   [B,N]  (1 = positive, 0 = negative)
// Output: float32 [B,4,H,W] = (iwe_pos, iwe_neg, iwe_pos_ts, iwe_neg_ts)

#define IMG_H 480
#define IMG_W 640

#define OT_H 32
#define OT_W 32
#define OTY (IMG_H / OT_H)        // 15
#define OTX (IMG_W / OT_W)        // 20
#define OT_PER_B (OTY * OTX)      // 300
#define NB 4
#define NT (NB * OT_PER_B)        // 1200

#define ACC_PLANE (OT_H * OT_W)   // 1024 cells

// ws layout (byte offsets)
#define CURS_STRIDE 16                  // u32 stride -> 64 B padded lines
#define WS_CURS 0                       // NT * 64 B = 76800
#define WS_SPILLCNT 76800               // 4 B
#define WS_SPILL 81920                  // SPILL_CAP * 16 B = 512 KB
#define SPILL_CAP 32768
#define WS_RECS 606208                  // drecs: NT * cap * 8 B

#define K1_THREADS 256
#define K1_IPT 8
#define K1_CHUNK (K1_THREADS * K1_IPT)  // 2048 events per block

#define DUP_INVALID 0xFFFFFFFFu

// tile-local coord quantization: q = (w - 32*dt + 1) * 1024, span [0, 34816)
#define QSCALE 1024.0f
#define INV_QSCALE 9.765625e-04f

#define Q20 1048576.0f
#define INV_Q20 9.5367431640625e-07f

// ---------------------------------------------------------------------------
// K1: warp + direct dest-tile counting scatter. XCD-affinity swizzle:
// block L -> XCD L%8 (heuristic); batch = bits[2:1] of L -> XCDs {2b,2b+1}.
__global__ void __launch_bounds__(K1_THREADS)
warp_scatter_kernel(const float* __restrict__ flow, const float* __restrict__ ts,
                    const int* __restrict__ ev_y, const int* __restrict__ ev_x,
                    const int* __restrict__ pol,
                    unsigned* __restrict__ dcurs, unsigned* __restrict__ spillcnt,
                    float4* __restrict__ spill, uint2* __restrict__ drecs,
                    int N, int cap, int nchunk) {
    __shared__ unsigned lh[OT_PER_B];     // per-dest-tile block-local counts
    __shared__ unsigned lbase[OT_PER_B];  // reserved global bases
    const int tid = threadIdx.x;
    const int L = blockIdx.x;
    const int b = (L >> 1) & 3;                    // batch -> XCD pair
    const int chunk = (L >> 3) * 2 + (L & 1);
    if (chunk >= nchunk) return;
    const int base = chunk * K1_CHUNK;

    for (int j = tid; j < OT_PER_B; j += K1_THREADS) lh[j] = 0;

    // Phase A1: coalesced event-field loads — all 4*IPT independent.
    int   eyK[K1_IPT], exK[K1_IPT], poK[K1_IPT];
    float tsK[K1_IPT];
    bool  vK[K1_IPT];
    #pragma unroll
    for (int k = 0; k < K1_IPT; ++k) {
        const int idx = base + k * K1_THREADS + tid;
        vK[k] = (idx < N);
        const int i = b * N + (vK[k] ? idx : 0);
        eyK[k] = ev_y[i];
        exK[k] = ev_x[i];
        tsK[k] = ts[i];
        poK[k] = pol[i];
    }

    // Phase A2: random flow gathers — 2*IPT loads issued back-to-back.
    const float* fb = flow + (size_t)b * 2 * IMG_H * IMG_W;
    float fxK[K1_IPT], fyK[K1_IPT];
    #pragma unroll
    for (int k = 0; k < K1_IPT; ++k) {
        const int pix = eyK[k] * IMG_W + exK[k];
        fxK[k] = fb[pix];
        fyK[k] = fb[IMG_H * IMG_W + pix];
    }

    __syncthreads();   // lh zeroing visible before ranking

    // Phase A3: warp + LDS rank. STATIC 4-slot dup table (rule #20):
    // slots = (row0/row1) x (col0/col1) tile combos; DUP_INVALID = unused.
    float wyK[K1_IPT], wxK[K1_IPT];
    unsigned metaK[K1_IPT];               // qt | pol<<15 (drec.y)
    unsigned dupS[K1_IPT][4];             // lt<<16 | rank, or DUP_INVALID

    #pragma unroll
    for (int k = 0; k < K1_IPT; ++k) {
        float wy = 0.f, wx = 0.f;
        unsigned meta = 0;
        unsigned d0 = DUP_INVALID, d1 = DUP_INVALID,
                 d2 = DUP_INVALID, d3 = DUP_INVALID;
        if (vK[k]) {
            const float t = tsK[k];
            const float dt = 1.0f - t;
            wy = (float)eyK[k] + dt * fyK[k];
            wx = (float)exK[k] + dt * fxK[k];
            const float nts = 1.0f - fabsf(1.0f - t);
            const int p = poK[k] & 1;
            int qt = __float2int_rn(nts * 32767.0f);
            qt = min(max(qt, 0), 32767);
            meta = (unsigned)qt | ((unsigned)p << 15);

            const int iy0 = (int)floorf(wy);
            const int ix0 = (int)floorf(wx);
            const int ry0 = iy0 >> 5;
            const int ry1 = (iy0 + 1) >> 5;
            const bool cy0 = (iy0 >= 0) && (iy0 < IMG_H);
            const bool cy1 = (iy0 + 1 >= 0) && (iy0 + 1 < IMG_H)
                             && (!cy0 || ry1 != ry0);
            const int rx0 = ix0 >> 5;
            const int rx1 = (ix0 + 1) >> 5;
            const bool cx0 = (ix0 >= 0) && (ix0 < IMG_W);
            const bool cx1 = (ix0 + 1 >= 0) && (ix0 + 1 < IMG_W)
                             && (!cx0 || rx1 != rx0);

            if (cy0 && cx0) {
                const unsigned lt = (unsigned)(ry0 * OTX + rx0);
                d0 = (lt << 16) | atomicAdd(&lh[lt], 1u);
            }
            if (cy0 && cx1) {
                const unsigned lt = (unsigned)(ry0 * OTX + rx1);
                d1 = (lt << 16) | atomicAdd(&lh[lt], 1u);
            }
            if (cy1 && cx0) {
                const unsigned lt = (unsigned)(ry1 * OTX + rx0);
                d2 = (lt << 16) | atomicAdd(&lh[lt], 1u);
            }
            if (cy1 && cx1) {
                const unsigned lt = (unsigned)(ry1 * OTX + rx1);
                d3 = (lt << 16) | atomicAdd(&lh[lt], 1u);
            }
        }
        wyK[k] = wy; wxK[k] = wx; metaK[k] = meta;
        dupS[k][0] = d0; dupS[k][1] = d1; dupS[k][2] = d2; dupS[k][3] = d3;
    }
    __syncthreads();

    // Phase B: reserve per-tile global ranges (1 padded atomic per nonzero).
    // Device-scope memory-side RMW (~23-25 ns marginal, v16/v17 pricing)
    // -> count minimized: 588 blocks x ~295 nonzero tiles ~ 174K total.
    for (int j = tid; j < OT_PER_B; j += K1_THREADS) {
        const unsigned n = lh[j];
        lbase[j] = n ? atomicAdd(&dcurs[(size_t)(b * OT_PER_B + j) * CURS_STRIDE], n)
                     : 0u;
    }
    __syncthreads();

    // Phase C: write dest-quantized records (static slot iteration)
    #pragma unroll
    for (int k = 0; k < K1_IPT; ++k) {
        #pragma unroll
        for (int d = 0; d < 4; ++d) {
            const unsigned dp = dupS[k][d];
            if (dp == DUP_INVALID) continue;
            const unsigned lt = dp >> 16;
            const unsigned rk = dp & 0xFFFFu;
            const int dty = (int)(lt / OTX);
            const int dtx = (int)(lt % OTX);
            const unsigned slot = lbase[lt] + rk;
            if (slot < (unsigned)cap) {
                int qy = __float2int_rn((wyK[k] - 32.0f * dty + 1.0f) * QSCALE);
                int qx = __float2int_rn((wxK[k] - 32.0f * dtx + 1.0f) * QSCALE);
                qy = min(max(qy, 0), 65535);
                qx = min(max(qx, 0), 65535);
                uint2 dr;
                dr.x = (unsigned)qy | ((unsigned)qx << 16);
                dr.y = metaK[k];
                drecs[(size_t)(b * OT_PER_B + lt) * cap + slot] = dr;
            } else {
                // restricted spill: applied only by tile (dty,dtx)
                const unsigned g = atomicAdd(spillcnt, 1u);
                if (g < SPILL_CAP) {
                    float4 s;
                    s.x = wyK[k]; s.y = wxK[k];
                    s.z = (float)(metaK[k] & 0x7FFFu) * (1.0f / 32767.0f);
                    s.w = __uint_as_float(0x80000000u
                            | (unsigned)((b << 1) | (metaK[k] >> 15))
                            | ((unsigned)dty << 8) | ((unsigned)dtx << 16));
                    spill[g] = s;
                }
            }
        }
    }
}

// ---------------------------------------------------------------------------
// K2: one block per ownership tile, same XCD-affinity swizzle.
__device__ __forceinline__ void
splat_rec(unsigned rx_, unsigned ry_, unsigned long long* __restrict__ acc64) {
    const float ry  = (float)(rx_ & 0xFFFFu) * INV_QSCALE - 1.0f;
    const float rx  = (float)(rx_ >> 16)     * INV_QSCALE - 1.0f;
    const float nts = (float)(ry_ & 0x7FFFu) * (1.0f / 32767.0f);
    const int p = (int)((ry_ >> 15) & 1u);
    const float byf = floorf(ry), bxf = floorf(rx);
    const int iy0 = (int)byf, ix0 = (int)bxf;
    const float ay = ry - byf, ax = rx - bxf;
    const float wyv[2] = {1.0f - ay, ay};
    const float wxv[2] = {1.0f - ax, ax};
    unsigned long long* accp = acc64 + (p ? 0 : 1) * ACC_PLANE;
    #pragma unroll
    for (int dy = 0; dy < 2; ++dy) {
        const int gy = iy0 + dy;
        if ((unsigned)gy >= (unsigned)OT_H) continue;
        #pragma unroll
        for (int dx = 0; dx < 2; ++dx) {
            const int gx = ix0 + dx;
            if ((unsigned)gx >= (unsigned)OT_W) continue;
            const float w = wyv[dy] * wxv[dx];
            const unsigned qw  = __float2uint_rn(w * Q20);
            const unsigned qwt = __float2uint_rn(w * nts * Q20);
            atomicAdd(&accp[gy * OT_W + gx],
                      ((unsigned long long)qwt << 32) | (unsigned long long)qw);
        }
    }
}

__global__ void __launch_bounds__(256)
splat_kernel(const uint2* __restrict__ drecs, const unsigned* __restrict__ dcurs,
             const float4* __restrict__ spill, const unsigned* __restrict__ spillcnt,
             float* __restrict__ out, int cap) {
    __shared__ unsigned long long acc64[2 * ACC_PLANE];  // [pol(pos,neg)][cell]
    const int L = blockIdx.x;
    const int myb = (L >> 1) & 3;                  // batch -> XCD pair
    const int rb  = (L >> 3) * 2 + (L & 1);        // 0..299
    const int tile = myb * OT_PER_B + rb;
    const int tid = threadIdx.x;
    #pragma unroll
    for (int j = tid; j < 2 * ACC_PLANE; j += 256) acc64[j] = 0ull;
    __syncthreads();

    const int sy  = rb / OTX;
    const int sx  = rb % OTX;

    const unsigned cnt = min(dcurs[(size_t)tile * CURS_STRIDE], (unsigned)cap);
    const uint2* recs = drecs + (size_t)tile * cap;
    const uint4* base4 = (const uint4*)recs;
    const unsigned npair = cnt >> 1;
    for (unsigned u = tid; u < npair; u += 256) {
        const uint4 q = base4[u];          // two records
        splat_rec(q.x, q.y, acc64);
        splat_rec(q.z, q.w, acc64);
    }
    if ((cnt & 1u) && tid == 0) {
        const uint2 r = recs[cnt - 1];
        splat_rec(r.x, r.y, acc64);
    }

    // fused spill application (normally zero records)
    const unsigned nsp = min(*spillcnt, (unsigned)SPILL_CAP);
    for (unsigned i = tid; i < nsp; i += 256) {
        const float4 s = spill[i];
        const unsigned meta = __float_as_uint(s.w);
        if ((int)((meta >> 1) & 3u) != myb) continue;
        if (meta & 0x80000000u) {   // restricted to one dest tile
            if ((int)((meta >> 8) & 31u) != sy || (int)((meta >> 16) & 31u) != sx)
                continue;
        }
        const int p = (int)(meta & 1u);
        const float wy = s.x, wx = s.y, nts = s.z;
        const float byf = floorf(wy), bxf = floorf(wx);
        const int iy0 = (int)byf, ix0 = (int)bxf;
        const float ay = wy - byf, ax = wx - bxf;
        const float wyv[2] = {1.0f - ay, ay};
        const float wxv[2] = {1.0f - ax, ax};
        unsigned long long* accp = acc64 + (p ? 0 : 1) * ACC_PLANE;
        #pragma unroll
        for (int dy = 0; dy < 2; ++dy) {
            const int gy = iy0 + dy;
            if ((gy >> 5) != sy) continue;       // ownership (global coords)
            #pragma unroll
            for (int dx = 0; dx < 2; ++dx) {
                const int gx = ix0 + dx;
                if ((gx >> 5) != sx) continue;
                const float w = wyv[dy] * wxv[dx];
                const unsigned qw  = __float2uint_rn(w * Q20);
                const unsigned qwt = __float2uint_rn(w * nts * Q20);
                atomicAdd(&accp[(gy & 31) * OT_W + (gx & 31)],
                          ((unsigned long long)qwt << 32) | (unsigned long long)qw);
            }
        }
    }
    __syncthreads();

    const int y0 = sy * OT_H;
    const int x0 = sx * OT_W;
    float* outb = out + (size_t)myb * 4 * IMG_H * IMG_W;
    for (int q = tid; q < 2 * (ACC_PLANE / 4); q += 256) {
        const int pl  = q / (ACC_PLANE / 4);     // 0 = pos, 1 = neg
        const int rem = q % (ACC_PLANE / 4);
        const int ry  = rem / (OT_W / 4);
        const int rx4 = rem % (OT_W / 4);
        float4 c4, t4;
        const unsigned long long* cell = acc64 + pl * ACC_PLANE + rem * 4;
        float* c = &c4.x; float* t = &t4.x;
        #pragma unroll
        for (int j = 0; j < 4; ++j) {
            const unsigned long long v = cell[j];
            c[j] = (float)(unsigned)(v & 0xFFFFFFFFull) * INV_Q20;
            t[j] = (float)(unsigned)(v >> 32) * INV_Q20;
        }
        const size_t off = (size_t)(y0 + ry) * IMG_W + x0 + rx4 * 4;
        *(float4*)(outb + (size_t)pl * IMG_H * IMG_W + off) = c4;
        *(float4*)(outb + (size_t)(pl + 2) * IMG_H * IMG_W + off) = t4;
    }
}

// ---------------------------------------------------------------------------
__device__ __forceinline__ void
warp_from(const float* __restrict__ flow, int b, int y, int x, float t,
          float& wy, float& wx, float& nts) {
    const float* fb = flow + (size_t)b * 2 * IMG_H * IMG_W;
    const int pix = y * IMG_W + x;
    const float fx = fb[pix];
    const float fy = fb[IMG_H * IMG_W + pix];
    const float dt = 1.0f - t;
    wy = (float)y + dt * fy;
    wx = (float)x + dt * fx;
    nts = 1.0f - fabsf(1.0f - t);
}

// Last-resort fallback: direct global atomics (needs zeroed out).
__global__ void __launch_bounds__(256)
event_splat_fallback(const float* __restrict__ flow, const float* __restrict__ ts,
                     const int* __restrict__ ev_y, const int* __restrict__ ev_x,
                     const int* __restrict__ pol, float* __restrict__ out,
                     int N, int total) {
    const int i = blockIdx.x * blockDim.x + threadIdx.x;
    if (i >= total) return;
    const int b = i / N;
    float wy, wx, nts;
    warp_from(flow, b, ev_y[i], ev_x[i], ts[i], wy, wx, nts);
    const int p = pol[i];
    const float byf = floorf(wy), bxf = floorf(wx);
    const int iy0 = (int)byf, ix0 = (int)bxf;
    const float ay = wy - byf, ax = wx - bxf;
    const float wyv[2] = {1.0f - ay, ay};
    const float wxv[2] = {1.0f - ax, ax};
    float* out_c = out + ((size_t)b * 4 + (p ? 0 : 1)) * IMG_H * IMG_W;
    float* out_t = out_c + 2 * IMG_H * IMG_W;
    #pragma unroll
    for (int dy = 0; dy < 2; ++dy) {
        const int gy = iy0 + dy;
        if (gy < 0 || gy >= IMG_H) continue;
        #pragma unroll
        for (int dx = 0; dx < 2; ++dx) {
            const int gx = ix0 + dx;
            if (gx < 0 || gx >= IMG_W) continue;
            const float w = wyv[dy] * wxv[dx];
            const int o = gy * IMG_W + gx;
            atomicAdd(out_c + o, w);
            atomicAdd(out_t + o, w * nts);
        }
    }
}

// ---------------------------------------------------------------------------
extern "C" void kernel_launch(void* const* d_in, const int* in_sizes, int n_in,
                              void* d_out, int out_size, void* d_ws, size_t ws_size,
                              hipStream_t stream) {
    const float* flow = (const float*)d_in[0];
    const float* ts   = (const float*)d_in[1];
    const int*   ev_y = (const int*)d_in[2];
    const int*   ev_x = (const int*)d_in[3];
    const int*   pol  = (const int*)d_in[4];
    float* out = (float*)d_out;

    const int total = in_sizes[2];                  // B*N
    const int B = out_size / (4 * IMG_H * IMG_W);
    const int N = total / B;
    char* ws = (char*)d_ws;

    // cap slots per dest tile: drec 8 B/slot. Mean load ~1063/tile
    // (300K events/batch x 1.063 dup / 300 tiles); spill absorbs stragglers.
    int cap = 0;
    if (ws_size > (size_t)WS_RECS)
        cap = (int)((ws_size - WS_RECS) / ((size_t)NT * 8));
    if (cap > 4096) cap = 4096;
    cap &= ~3;

    if (B == NB && cap >= 1280) {
        unsigned* dcurs    = (unsigned*)(ws + WS_CURS);
        unsigned* spillcnt = (unsigned*)(ws + WS_SPILLCNT);
        float4*   spill    = (float4*)(ws + WS_SPILL);
        uint2*    drecs    = (uint2*)(ws + WS_RECS);

        hipMemsetAsync(ws, 0, WS_SPILL, stream);    // dcurs + spillcnt

        const int nchunk = (N + K1_CHUNK - 1) / K1_CHUNK;            // 147
        const int g1 = 8 * ((nchunk + 1) / 2);                       // 592
        warp_scatter_kernel<<<g1, K1_THREADS, 0, stream>>>(
            flow, ts, ev_y, ev_x, pol, dcurs, spillcnt, spill, drecs,
            N, cap, nchunk);
        splat_kernel<<<NT, 256, 0, stream>>>(drecs, dcurs, spill, spillcnt,
                                             out, cap);
        return;
    }

    // last resort
    hipMemsetAsync(d_out, 0, (size_t)out_size * sizeof(float), stream);
    const int blocks = (total + 255) / 256;
    event_splat_fallback<<<blocks, 256, 0, stream>>>(flow, ts, ev_y, ev_x, pol,
                                                     out, N, total);
}